// Round 3
// baseline (741.123 us; speedup 1.0000x reference)
//
#include <hip/hip_runtime.h>
#include <hip/hip_bf16.h>
#include <math.h>

#define BB 16
#define NN_ 1024
#define TT 12

typedef __attribute__((ext_vector_type(8))) short bf16x8;
typedef __attribute__((ext_vector_type(4))) float f32x4;

// ---------------- workspace layout (float units) ----------------
static const size_t ACC_OFF    = 0;          // 16
static const size_t COLSUM_OFF = 16;         // B*N = 16384
static const size_t TAT_OFF    = 16400;      // B*T*T = 2304
static const size_t LHST_OFF   = 18704;      // B*N*T = 196608
static const size_t RHS2_OFF   = 215312;     // B*T*N = 196608
static const size_t VSB_OFF    = 411920;     // N*N bf16 = 524288 floats
static const size_t SIG2B_OFF  = 936208;     // B*N*N bf16 = 8388608 floats
static const size_t CHEBB_OFF  = 9324816;    // 3*N*N bf16 = 1572864 floats
static const size_t EXPS_OFF   = 10897680;   // B*N*N bf16 = 8388608 floats
static const size_t RHSC_OFF   = 19286288;   // B*K*N*F*T fp32 = 1769472
// total 21055760 floats = ~84 MB

__device__ __forceinline__ float wave_reduce_sum(float v) {
    #pragma unroll
    for (int off = 32; off > 0; off >>= 1) v += __shfl_down(v, off);
    return v;
}

__device__ __forceinline__ unsigned short f2b(float f) {
    __hip_bfloat16 h = __float2bfloat16(f);
    return *(unsigned short*)&h;
}
__device__ __forceinline__ float b2f(unsigned short u) {
    return __uint_as_float(((unsigned int)u) << 16);
}

// ---------------- init: zero acc + colsum + rhsc ----------------
__global__ void k_init(float* __restrict__ ws) {
    int i = blockIdx.x * 256 + threadIdx.x;
    if (i < 16400) ws[i] = 0.f;
    float4* r4 = (float4*)(ws + RHSC_OFF);
    if (i < 442368) r4[i] = make_float4(0.f, 0.f, 0.f, 0.f);
}

// ---------------- temporal attention -> tat (B,T,T) ----------------
__global__ __launch_bounds__(64) void k_temporal(
    const float* __restrict__ x, const float* __restrict__ U1,
    const float* __restrict__ U2, const float* __restrict__ U3,
    const float* __restrict__ be, const float* __restrict__ Ve,
    float* __restrict__ tat)
{
    const int b = blockIdx.x;
    const int lane = threadIdx.x;
    float lA[36], lM[36];
    #pragma unroll
    for (int i = 0; i < 36; ++i) { lA[i] = 0.f; lM[i] = 0.f; }
    const float u30 = U3[0], u31 = U3[1], u32 = U3[2];
    for (int n = lane; n < NN_; n += 64) {
        const float* xp = x + ((size_t)b * NN_ + n) * 36;
        float xr[36];
        #pragma unroll
        for (int i = 0; i < 9; ++i) *(float4*)&xr[i*4] = *(const float4*)(xp + i*4);
        const float u1  = U1[n];
        const float u20 = U2[n], u21 = U2[NN_ + n], u22 = U2[2*NN_ + n];
        #pragma unroll
        for (int t = 0; t < 12; ++t) {
            float ru = xr[t]*u30 + xr[12+t]*u31 + xr[24+t]*u32;
            lM[t]    += u20 * ru;
            lM[12+t] += u21 * ru;
            lM[24+t] += u22 * ru;
            lA[t]    += xr[t]    * u1;
            lA[12+t] += xr[12+t] * u1;
            lA[24+t] += xr[24+t] * u1;
        }
    }
    __shared__ float tA[36], tM[36], sgs[144], es[144], cmax[12], csum[12];
    #pragma unroll
    for (int i = 0; i < 36; ++i) {
        float v = wave_reduce_sum(lA[i]);
        if (lane == 0) tA[i] = v;
        float w = wave_reduce_sum(lM[i]);
        if (lane == 0) tM[i] = w;
    }
    __syncthreads();
    for (int idx = lane; idx < 144; idx += 64) {
        int t = idx / 12, u = idx % 12;
        float p = tA[t]*tM[u] + tA[12+t]*tM[12+u] + tA[24+t]*tM[24+u];
        p += be[idx];
        sgs[idx] = 1.f / (1.f + expf(-p));
    }
    __syncthreads();
    for (int idx = lane; idx < 144; idx += 64) {
        int i = idx / 12, j = idx % 12;
        float e = 0.f;
        #pragma unroll
        for (int k = 0; k < 12; ++k) e += sgs[i*12 + k] * Ve[j*12 + k];
        es[idx] = e;
    }
    __syncthreads();
    if (lane < 12) {
        int j = lane;
        float m = -1e30f;
        for (int i = 0; i < 12; ++i) m = fmaxf(m, es[i*12 + j]);
        float sx = 0.f;
        for (int i = 0; i < 12; ++i) sx += expf(es[i*12 + j] - m);
        cmax[j] = m; csum[j] = sx;
    }
    __syncthreads();
    for (int idx = lane; idx < 144; idx += 64) {
        int j = idx % 12;
        tat[(size_t)b*144 + idx] = expf(es[idx] - cmax[j]) / csum[j];
    }
}

// ---------------- x_tat projections -> lhsT (B,N,T), rhs2 (B,T,N) ----------------
__global__ __launch_bounds__(256) void k_xtat(
    const float* __restrict__ x, const float* __restrict__ tat,
    const float* __restrict__ W1, const float* __restrict__ W2,
    const float* __restrict__ W3,
    float* __restrict__ lhsT, float* __restrict__ rhs2)
{
    const int id = blockIdx.x * 256 + threadIdx.x;
    const int b = id >> 10, n = id & 1023;
    const float* xp = x + (size_t)id * 36;
    float xr[36];
    #pragma unroll
    for (int i = 0; i < 9; ++i) *(float4*)&xr[i*4] = *(const float4*)(xp + i*4);
    const float* tp = tat + (size_t)b * 144;
    float xt[36];
    #pragma unroll
    for (int f = 0; f < 3; ++f)
        #pragma unroll
        for (int u = 0; u < 12; ++u) {
            float s = 0.f;
            #pragma unroll
            for (int t = 0; t < 12; ++t) s += xr[f*12 + t] * tp[t*12 + u];
            xt[f*12 + u] = s;
        }
    float lA0 = 0.f, lA1 = 0.f, lA2 = 0.f;
    #pragma unroll
    for (int t = 0; t < 12; ++t) {
        float w = W1[t];
        lA0 += xt[t]*w; lA1 += xt[12+t]*w; lA2 += xt[24+t]*w;
    }
    #pragma unroll
    for (int t2 = 0; t2 < 12; ++t2)
        lhsT[(size_t)id*12 + t2] = lA0*W2[t2] + lA1*W2[12+t2] + lA2*W2[24+t2];
    const float w30 = W3[0], w31 = W3[1], w32 = W3[2];
    #pragma unroll
    for (int u = 0; u < 12; ++u)
        rhs2[((size_t)b*12 + u)*NN_ + n] = xt[u]*w30 + xt[12+u]*w31 + xt[24+u]*w32;
}

// ---------------- sig2 (B,N,N) -> bf16 ----------------
__global__ __launch_bounds__(256) void k_sig2(
    const float* __restrict__ lhsT, const float* __restrict__ rhs2,
    const float* __restrict__ bs, __hip_bfloat16* __restrict__ sig2b)
{
    const unsigned int idx = blockIdx.x * 256u + threadIdx.x;
    const int m = (int)(idx & 1023u);
    const unsigned int bn = idx >> 10;
    const int b = (int)(bn >> 10);
    const int n = (int)(bn & 1023u);
    const float* lp = lhsT + (size_t)bn * 12;
    const float* rp = rhs2 + (size_t)b * 12 * NN_ + m;
    float z = bs[(size_t)n * NN_ + m];
    #pragma unroll
    for (int t = 0; t < 12; ++t) z += lp[t] * rp[(size_t)t * NN_];
    sig2b[idx] = __float2bfloat16(1.f / (1.f + expf(-z)));
}

// ---------------- fp32 -> bf16 converters ----------------
__global__ __launch_bounds__(256) void k_cvt4(
    const float* __restrict__ src, unsigned short* __restrict__ dst)
{
    const int i = blockIdx.x * 256 + threadIdx.x;
    float4 v = ((const float4*)src)[i];
    ushort4 o;
    o.x = f2b(v.x); o.y = f2b(v.y); o.z = f2b(v.z); o.w = f2b(v.w);
    ((ushort4*)dst)[i] = o;
}

// ---------------- S = sig2 @ Vs^T, fused exp + colsum; store expS bf16 ----------------
__global__ __launch_bounds__(256) void k_gemm_s_mfma(
    const short* __restrict__ A,   // sig2b [B][1024][1024] bf16
    const short* __restrict__ Bm,  // Vsb   [1024][1024] bf16
    unsigned short* __restrict__ E, // expS bf16 out
    float* __restrict__ colsum)
{
    __shared__ short As[128 * 32];
    __shared__ short Bs[128 * 32];
    const int b  = blockIdx.z;
    const int i0 = blockIdx.y * 128;
    const int j0 = blockIdx.x * 128;
    const int tid = threadIdx.x;
    const int wid = tid >> 6;
    const int lane = tid & 63;
    const int wr = wid & 1, wc = wid >> 1;
    const short* Ab = A + (size_t)b * NN_ * NN_;

    f32x4 acc[4][4];
    const f32x4 z4 = {0.f, 0.f, 0.f, 0.f};
    #pragma unroll
    for (int m = 0; m < 4; ++m)
        #pragma unroll
        for (int n = 0; n < 4; ++n) acc[m][n] = z4;

    const int srow = lane >> 2;
    const int schk = lane & 3;
    const int fr = lane & 15;
    const int kb = (lane >> 4) * 8;

    for (int k0 = 0; k0 < NN_; k0 += 32) {
        #pragma unroll
        for (int q = 0; q < 2; ++q) {
            const int rb = (wid * 2 + q) * 16;
            const short* srcA = Ab + (size_t)(i0 + rb + srow) * NN_ + k0 + schk * 8;
            const short* srcB = Bm + (size_t)(j0 + rb + srow) * NN_ + k0 + schk * 8;
            __builtin_amdgcn_global_load_lds(
                (const __attribute__((address_space(1))) unsigned int*)srcA,
                (__attribute__((address_space(3))) unsigned int*)(As + rb * 32), 16, 0, 0);
            __builtin_amdgcn_global_load_lds(
                (const __attribute__((address_space(1))) unsigned int*)srcB,
                (__attribute__((address_space(3))) unsigned int*)(Bs + rb * 32), 16, 0, 0);
        }
        __syncthreads();
        bf16x8 aF[4], bF[4];
        #pragma unroll
        for (int m = 0; m < 4; ++m)
            aF[m] = *(const bf16x8*)(As + (wr*64 + m*16 + fr) * 32 + kb);
        #pragma unroll
        for (int n = 0; n < 4; ++n)
            bF[n] = *(const bf16x8*)(Bs + (wc*64 + n*16 + fr) * 32 + kb);
        #pragma unroll
        for (int m = 0; m < 4; ++m)
            #pragma unroll
            for (int n = 0; n < 4; ++n)
                acc[m][n] = __builtin_amdgcn_mfma_f32_16x16x32_bf16(aF[m], bF[n], acc[m][n], 0, 0, 0);
        __syncthreads();
    }
    unsigned short* Ep = E + (size_t)b * NN_ * NN_;
    const int cn = lane & 15;
    const int r0 = (lane >> 4) * 4;
    float cs[4] = {0.f, 0.f, 0.f, 0.f};
    #pragma unroll
    for (int m = 0; m < 4; ++m)
        #pragma unroll
        for (int n = 0; n < 4; ++n)
            #pragma unroll
            for (int r = 0; r < 4; ++r) {
                float e = __expf(acc[m][n][r]);
                Ep[(size_t)(i0 + wr*64 + m*16 + r0 + r) * NN_ + j0 + wc*64 + n*16 + cn] = f2b(e);
                cs[n] += e;
            }
    #pragma unroll
    for (int n = 0; n < 4; ++n) {
        float s = cs[n];
        s += __shfl_xor(s, 16);
        s += __shfl_xor(s, 32);
        if (lane < 16)
            atomicAdd(&colsum[b * NN_ + j0 + wc*64 + n*16 + cn], s);
    }
}

// ---- rhs_c[b,k,m,f,t] += sum_n chebb[k,n,m]*expS[b,n,m]*rcs[m]*x[b,n,f,t] ----
__global__ __launch_bounds__(256) void k_rhsc(
    const unsigned short* __restrict__ chebb, const unsigned short* __restrict__ expS,
    const float* __restrict__ colsum, const float* __restrict__ x,
    float* __restrict__ rhsc)
{
    __shared__ float ch[3][16][64];
    __shared__ float st[16][64];
    __shared__ float xs[16][36];
    const int m0 = blockIdx.x * 64;
    const int b  = blockIdx.y;
    const int nbase = blockIdx.z * 512;
    const int tid = threadIdx.x;
    const int m = tid >> 2, q = tid & 3;
    const int nn = tid >> 4, mm = (tid & 15) << 2;
    float4 rcs;
    {
        const float* cp = colsum + b * NN_ + m0 + mm;
        rcs.x = 1.f / cp[0]; rcs.y = 1.f / cp[1];
        rcs.z = 1.f / cp[2]; rcs.w = 1.f / cp[3];
    }
    float acc[3][9];
    #pragma unroll
    for (int k = 0; k < 3; ++k)
        #pragma unroll
        for (int jj = 0; jj < 9; ++jj) acc[k][jj] = 0.f;

    const unsigned short* sb = expS + (size_t)b * NN_ * NN_;
    const float* xb = x + (size_t)b * NN_ * 36;
    for (int n0 = nbase; n0 < nbase + 512; n0 += 16) {
        #pragma unroll
        for (int k = 0; k < 3; ++k) {
            ushort4 u = *(const ushort4*)(chebb + (size_t)k * NN_ * NN_ + (size_t)(n0 + nn) * NN_ + m0 + mm);
            ch[k][nn][mm+0] = b2f(u.x); ch[k][nn][mm+1] = b2f(u.y);
            ch[k][nn][mm+2] = b2f(u.z); ch[k][nn][mm+3] = b2f(u.w);
        }
        {
            ushort4 u = *(const ushort4*)(sb + (size_t)(n0 + nn) * NN_ + m0 + mm);
            st[nn][mm+0] = b2f(u.x) * rcs.x; st[nn][mm+1] = b2f(u.y) * rcs.y;
            st[nn][mm+2] = b2f(u.z) * rcs.z; st[nn][mm+3] = b2f(u.w) * rcs.w;
        }
        if (tid < 144) {
            int n2 = tid / 9, q2 = tid - n2 * 9;
            *(float4*)&xs[n2][q2*4] = *(const float4*)(xb + (size_t)(n0 + n2) * 36 + q2*4);
        }
        __syncthreads();
        #pragma unroll
        for (int u = 0; u < 16; ++u) {
            float xv[9];
            #pragma unroll
            for (int jj = 0; jj < 9; ++jj) xv[jj] = xs[u][q*9 + jj];
            const float sv = st[u][m];
            #pragma unroll
            for (int k = 0; k < 3; ++k) {
                const float w = ch[k][u][m] * sv;
                #pragma unroll
                for (int jj = 0; jj < 9; ++jj) acc[k][jj] += w * xv[jj];
            }
        }
        __syncthreads();
    }
    #pragma unroll
    for (int k = 0; k < 3; ++k) {
        float* rp = rhsc + (((size_t)b*3 + k) * NN_ + m0 + m) * 36 + q*9;
        #pragma unroll
        for (int jj = 0; jj < 9; ++jj) atomicAdd(&rp[jj], acc[k][jj]);
    }
}

// ---- fused gcn + MFMA tconv + residual + relu + stats -> y ----
// out[c, nt] = sum_k W[c,k] * G[k, nt],  k = 3*cp + d,  G[k, (i,t)] = g[cp][t+d-1]
#define GSTR 200
__global__ __launch_bounds__(256) void k_y3(
    const float* __restrict__ rhsc, const float* __restrict__ Theta,
    const float* __restrict__ x,
    const float* __restrict__ tcw, const float* __restrict__ tcb,
    const float* __restrict__ rcw, const float* __restrict__ rcb,
    float* __restrict__ y, float* __restrict__ acc)
{
    __shared__ unsigned short Gs[96 * GSTR];   // 37.5 KB
    __shared__ unsigned short Ws[64 * GSTR];   // 25 KB
    __shared__ float xls[8 * 36];              // 1.125 KB
    const int tid = threadIdx.x;
    const int wid = tid >> 6, lane = tid & 63;
    const int blk = blockIdx.x;                // items blk*8 .. blk*8+7

    // stage Ws (tcw rows -> bf16), thread handles floats [tid*48, tid*48+48)
    {
        const int rw = tid >> 2;               // row c = tid/4 (since 192/48=4)
        const int ko = (tid & 3) * 48;         // k offset
        const float* src = tcw + rw * 192 + ko;
        unsigned int* dst = (unsigned int*)(Ws) ;
        #pragma unroll
        for (int j = 0; j < 12; ++j) {
            float4 v = *(const float4*)(src + j*4);
            unsigned int p0 = (unsigned int)f2b(v.x) | ((unsigned int)f2b(v.y) << 16);
            unsigned int p1 = (unsigned int)f2b(v.z) | ((unsigned int)f2b(v.w) << 16);
            dst[(rw * GSTR + ko) / 2 + j*2]     = p0;
            dst[(rw * GSTR + ko) / 2 + j*2 + 1] = p1;
        }
    }
    if (tid < 72)
        ((float4*)xls)[tid] = ((const float4*)(x + (size_t)blk * 8 * 36))[tid];

    // gcn phase: wave wid computes items {2*wid, 2*wid+1}, lane = channel c
    float th[9];
    #pragma unroll
    for (int j = 0; j < 9; ++j) th[j] = Theta[j * 64 + lane];
    #pragma unroll
    for (int ii = 0; ii < 2; ++ii) {
        const int i = wid * 2 + ii;
        const int bn = blk * 8 + i;
        const int b = bn >> 10, n = bn & 1023;
        float g[12];
        #pragma unroll
        for (int t = 0; t < 12; ++t) g[t] = 0.f;
        #pragma unroll
        for (int k = 0; k < 3; ++k) {
            const float* rp = rhsc + (((size_t)b*3 + k) * NN_ + n) * 36;
            #pragma unroll
            for (int f = 0; f < 3; ++f) {
                float4 v0 = *(const float4*)(rp + f*12);
                float4 v1 = *(const float4*)(rp + f*12 + 4);
                float4 v2 = *(const float4*)(rp + f*12 + 8);
                const float w = th[k*3 + f];
                g[0] += v0.x*w; g[1] += v0.y*w; g[2]  += v0.z*w; g[3]  += v0.w*w;
                g[4] += v1.x*w; g[5] += v1.y*w; g[6]  += v1.z*w; g[7]  += v1.w*w;
                g[8] += v2.x*w; g[9] += v2.y*w; g[10] += v2.z*w; g[11] += v2.w*w;
            }
        }
        unsigned short gb[14];
        gb[0] = 0; gb[13] = 0;
        #pragma unroll
        for (int t = 0; t < 12; ++t) gb[t+1] = f2b(fmaxf(g[t], 0.f));
        #pragma unroll
        for (int t = 0; t < 12; ++t) {
            unsigned short* p = Gs + (i*12 + t) * GSTR + 3*lane;
            p[0] = gb[t]; p[1] = gb[t+1]; p[2] = gb[t+2];
        }
    }
    __syncthreads();

    // MFMA phase: wave wid -> c-tile wid (c = wid*16 + (lane&15))
    const int cl = lane & 15, kg = lane >> 4;
    const int c = wid * 16 + cl;
    bf16x8 bW[6];
    #pragma unroll
    for (int ks = 0; ks < 6; ++ks)
        bW[ks] = *(const bf16x8*)(Ws + c * GSTR + kg*8 + 32*ks);
    const float tb = tcb[c];
    const float rw0 = rcw[c*3], rw1 = rcw[c*3+1], rw2 = rcw[c*3+2];
    const float rbv = rcb[c];
    float ls = 0.f, lss = 0.f;
    #pragma unroll
    for (int ct = 0; ct < 6; ++ct) {
        f32x4 a4 = {0.f, 0.f, 0.f, 0.f};
        const int col = ct * 16 + cl;
        #pragma unroll
        for (int ks = 0; ks < 6; ++ks) {
            bf16x8 aF = *(const bf16x8*)(Gs + col * GSTR + kg*8 + 32*ks);
            a4 = __builtin_amdgcn_mfma_f32_16x16x32_bf16(aF, bW[ks], a4, 0, 0, 0);
        }
        #pragma unroll
        for (int r = 0; r < 4; ++r) {
            const int nt = ct * 16 + kg * 4 + r;
            const int i = nt / 12;
            const int t = nt - i * 12;
            const float xres = rbv + xls[i*36 + t]*rw0 + xls[i*36 + 12 + t]*rw1 + xls[i*36 + 24 + t]*rw2;
            const float v = fmaxf(xres + a4[r] + tb, 0.f);
            ls += v; lss += v * v;
            y[(size_t)(blk*8 + i) * 768 + c * 12 + t] = v;
        }
    }
    ls  = wave_reduce_sum(ls);
    lss = wave_reduce_sum(lss);
    if (lane == 0) { atomicAdd(&acc[0], ls); atomicAdd(&acc[1], lss); }
}

// ---------------- finalize mean / inv_std ----------------
__global__ void k_fin(float* __restrict__ acc) {
    const float cnt = (float)((size_t)BB * NN_ * 64 * TT);
    float mu = acc[0] / cnt;
    float var = acc[1] / cnt - mu * mu;
    acc[2] = mu;
    acc[3] = rsqrtf(var + 1e-5f);
}

// ---------------- normalize in place on d_out ----------------
__global__ __launch_bounds__(256) void k_norm(
    float* __restrict__ y, const float* __restrict__ lng,
    const float* __restrict__ lnb, const float* __restrict__ acc)
{
    const unsigned int i = blockIdx.x * 256u + threadIdx.x;
    const float mu = acc[2], inv = acc[3];
    float4 v  = ((const float4*)y)[i];
    float4 gv = ((const float4*)lng)[i];
    float4 bv = ((const float4*)lnb)[i];
    v.x = (v.x - mu) * inv * gv.x + bv.x;
    v.y = (v.y - mu) * inv * gv.y + bv.y;
    v.z = (v.z - mu) * inv * gv.z + bv.z;
    v.w = (v.w - mu) * inv * gv.w + bv.w;
    ((float4*)y)[i] = v;
}

extern "C" void kernel_launch(void* const* d_in, const int* in_sizes, int n_in,
                              void* d_out, int out_size, void* d_ws, size_t ws_size,
                              hipStream_t stream)
{
    const float* x    = (const float*)d_in[0];
    const float* U1   = (const float*)d_in[1];
    const float* U2   = (const float*)d_in[2];
    const float* U3   = (const float*)d_in[3];
    const float* be   = (const float*)d_in[4];
    const float* Ve   = (const float*)d_in[5];
    const float* W1   = (const float*)d_in[6];
    const float* W2   = (const float*)d_in[7];
    const float* W3   = (const float*)d_in[8];
    const float* bs   = (const float*)d_in[9];
    const float* Vs   = (const float*)d_in[10];
    const float* cheb = (const float*)d_in[11];
    const float* Th   = (const float*)d_in[12];
    const float* tcw  = (const float*)d_in[13];
    const float* tcb  = (const float*)d_in[14];
    const float* rcw  = (const float*)d_in[15];
    const float* rcb  = (const float*)d_in[16];
    const float* lng  = (const float*)d_in[17];
    const float* lnb  = (const float*)d_in[18];
    float* out = (float*)d_out;
    float* ws  = (float*)d_ws;

    float* acc    = ws + ACC_OFF;
    float* colsum = ws + COLSUM_OFF;
    float* tat    = ws + TAT_OFF;
    float* lhsT   = ws + LHST_OFF;
    float* rhs2   = ws + RHS2_OFF;
    unsigned short* Vsb   = (unsigned short*)(ws + VSB_OFF);
    unsigned short* sig2b = (unsigned short*)(ws + SIG2B_OFF);
    unsigned short* chebb = (unsigned short*)(ws + CHEBB_OFF);
    unsigned short* expS  = (unsigned short*)(ws + EXPS_OFF);
    float* rhsc   = ws + RHSC_OFF;

    k_init<<<1728, 256, 0, stream>>>(ws);
    k_temporal<<<BB, 64, 0, stream>>>(x, U1, U2, U3, be, Ve, tat);
    k_xtat<<<(BB * NN_) / 256, 256, 0, stream>>>(x, tat, W1, W2, W3, lhsT, rhs2);
    k_cvt4<<<(NN_ * NN_) / 1024, 256, 0, stream>>>(Vs, Vsb);
    k_cvt4<<<(3 * NN_ * NN_) / 1024, 256, 0, stream>>>(cheb, chebb);
    k_sig2<<<(BB * NN_ * NN_) / 256, 256, 0, stream>>>(lhsT, rhs2, bs, (__hip_bfloat16*)sig2b);
    k_gemm_s_mfma<<<dim3(8, 8, BB), 256, 0, stream>>>((const short*)sig2b, (const short*)Vsb, expS, colsum);
    k_rhsc<<<dim3(16, BB, 2), 256, 0, stream>>>(chebb, expS, colsum, x, rhsc);
    k_y3<<<(BB * NN_) / 8, 256, 0, stream>>>(rhsc, Th, x, tcw, tcb, rcw, rcb, out, acc);
    k_fin<<<1, 1, 0, stream>>>(acc);
    k_norm<<<(BB * NN_ * 64 * TT) / 4 / 256, 256, 0, stream>>>(out, lng, lnb, acc);
}

// Round 4
// 541.951 us; speedup vs baseline: 1.3675x; 1.3675x over previous
//
#include <hip/hip_runtime.h>
#include <hip/hip_bf16.h>
#include <math.h>

#define BB 16
#define NN_ 1024
#define TT 12

typedef __attribute__((ext_vector_type(8))) short bf16x8;
typedef __attribute__((ext_vector_type(4))) float f32x4;

// ---------------- workspace layout (float units) ----------------
static const size_t ACC_OFF    = 0;          // 16
static const size_t COLSUM_OFF = 16;         // B*N = 16384
static const size_t TAT_OFF    = 16400;      // B*T*T = 2304
static const size_t LHST_OFF   = 18704;      // B*N*T = 196608
static const size_t RHS2_OFF   = 215312;     // B*T*N = 196608
static const size_t VSB_OFF    = 411920;     // N*N bf16 = 524288 floats
static const size_t SIG2B_OFF  = 936208;     // B*N*N bf16 = 8388608 floats
static const size_t CHEBB_OFF  = 9324816;    // 3*N*N bf16 = 1572864 floats
static const size_t EXPS_OFF   = 10897680;   // B*N*N bf16 = 8388608 floats
static const size_t RHSC0_OFF  = 19286288;   // B*K*N*F*T fp32 = 1769472
static const size_t RHSC1_OFF  = 21055760;   // B*K*N*F*T fp32 = 1769472
// total 22825232 floats = ~91 MB

__device__ __forceinline__ float wave_reduce_sum(float v) {
    #pragma unroll
    for (int off = 32; off > 0; off >>= 1) v += __shfl_down(v, off);
    return v;
}

__device__ __forceinline__ unsigned short f2b(float f) {
    __hip_bfloat16 h = __float2bfloat16(f);
    return *(unsigned short*)&h;
}
__device__ __forceinline__ float b2f(unsigned short u) {
    return __uint_as_float(((unsigned int)u) << 16);
}

// ---------------- init: zero acc + colsum ----------------
__global__ void k_init(float* __restrict__ ws) {
    int i = blockIdx.x * 256 + threadIdx.x;
    if (i < 16400) ws[i] = 0.f;
}

// ---------------- temporal attention -> tat (B,T,T) ----------------
__global__ __launch_bounds__(64) void k_temporal(
    const float* __restrict__ x, const float* __restrict__ U1,
    const float* __restrict__ U2, const float* __restrict__ U3,
    const float* __restrict__ be, const float* __restrict__ Ve,
    float* __restrict__ tat)
{
    const int b = blockIdx.x;
    const int lane = threadIdx.x;
    float lA[36], lM[36];
    #pragma unroll
    for (int i = 0; i < 36; ++i) { lA[i] = 0.f; lM[i] = 0.f; }
    const float u30 = U3[0], u31 = U3[1], u32 = U3[2];
    for (int n = lane; n < NN_; n += 64) {
        const float* xp = x + ((size_t)b * NN_ + n) * 36;
        float xr[36];
        #pragma unroll
        for (int i = 0; i < 9; ++i) *(float4*)&xr[i*4] = *(const float4*)(xp + i*4);
        const float u1  = U1[n];
        const float u20 = U2[n], u21 = U2[NN_ + n], u22 = U2[2*NN_ + n];
        #pragma unroll
        for (int t = 0; t < 12; ++t) {
            float ru = xr[t]*u30 + xr[12+t]*u31 + xr[24+t]*u32;
            lM[t]    += u20 * ru;
            lM[12+t] += u21 * ru;
            lM[24+t] += u22 * ru;
            lA[t]    += xr[t]    * u1;
            lA[12+t] += xr[12+t] * u1;
            lA[24+t] += xr[24+t] * u1;
        }
    }
    __shared__ float tA[36], tM[36], sgs[144], es[144], cmax[12], csum[12];
    #pragma unroll
    for (int i = 0; i < 36; ++i) {
        float v = wave_reduce_sum(lA[i]);
        if (lane == 0) tA[i] = v;
        float w = wave_reduce_sum(lM[i]);
        if (lane == 0) tM[i] = w;
    }
    __syncthreads();
    for (int idx = lane; idx < 144; idx += 64) {
        int t = idx / 12, u = idx % 12;
        float p = tA[t]*tM[u] + tA[12+t]*tM[12+u] + tA[24+t]*tM[24+u];
        p += be[idx];
        sgs[idx] = 1.f / (1.f + expf(-p));
    }
    __syncthreads();
    for (int idx = lane; idx < 144; idx += 64) {
        int i = idx / 12, j = idx % 12;
        float e = 0.f;
        #pragma unroll
        for (int k = 0; k < 12; ++k) e += sgs[i*12 + k] * Ve[j*12 + k];
        es[idx] = e;
    }
    __syncthreads();
    if (lane < 12) {
        int j = lane;
        float m = -1e30f;
        for (int i = 0; i < 12; ++i) m = fmaxf(m, es[i*12 + j]);
        float sx = 0.f;
        for (int i = 0; i < 12; ++i) sx += expf(es[i*12 + j] - m);
        cmax[j] = m; csum[j] = sx;
    }
    __syncthreads();
    for (int idx = lane; idx < 144; idx += 64) {
        int j = idx % 12;
        tat[(size_t)b*144 + idx] = expf(es[idx] - cmax[j]) / csum[j];
    }
}

// ---------------- x_tat projections -> lhsT (B,N,T), rhs2 (B,T,N) ----------------
__global__ __launch_bounds__(256) void k_xtat(
    const float* __restrict__ x, const float* __restrict__ tat,
    const float* __restrict__ W1, const float* __restrict__ W2,
    const float* __restrict__ W3,
    float* __restrict__ lhsT, float* __restrict__ rhs2)
{
    const int id = blockIdx.x * 256 + threadIdx.x;
    const int b = id >> 10, n = id & 1023;
    const float* xp = x + (size_t)id * 36;
    float xr[36];
    #pragma unroll
    for (int i = 0; i < 9; ++i) *(float4*)&xr[i*4] = *(const float4*)(xp + i*4);
    const float* tp = tat + (size_t)b * 144;
    float xt[36];
    #pragma unroll
    for (int f = 0; f < 3; ++f)
        #pragma unroll
        for (int u = 0; u < 12; ++u) {
            float s = 0.f;
            #pragma unroll
            for (int t = 0; t < 12; ++t) s += xr[f*12 + t] * tp[t*12 + u];
            xt[f*12 + u] = s;
        }
    float lA0 = 0.f, lA1 = 0.f, lA2 = 0.f;
    #pragma unroll
    for (int t = 0; t < 12; ++t) {
        float w = W1[t];
        lA0 += xt[t]*w; lA1 += xt[12+t]*w; lA2 += xt[24+t]*w;
    }
    #pragma unroll
    for (int t2 = 0; t2 < 12; ++t2)
        lhsT[(size_t)id*12 + t2] = lA0*W2[t2] + lA1*W2[12+t2] + lA2*W2[24+t2];
    const float w30 = W3[0], w31 = W3[1], w32 = W3[2];
    #pragma unroll
    for (int u = 0; u < 12; ++u)
        rhs2[((size_t)b*12 + u)*NN_ + n] = xt[u]*w30 + xt[12+u]*w31 + xt[24+u]*w32;
}

// ---------------- sig2 (B,N,N) -> bf16 ----------------
__global__ __launch_bounds__(256) void k_sig2(
    const float* __restrict__ lhsT, const float* __restrict__ rhs2,
    const float* __restrict__ bs, __hip_bfloat16* __restrict__ sig2b)
{
    const unsigned int idx = blockIdx.x * 256u + threadIdx.x;
    const int m = (int)(idx & 1023u);
    const unsigned int bn = idx >> 10;
    const int b = (int)(bn >> 10);
    const int n = (int)(bn & 1023u);
    const float* lp = lhsT + (size_t)bn * 12;
    const float* rp = rhs2 + (size_t)b * 12 * NN_ + m;
    float z = bs[(size_t)n * NN_ + m];
    #pragma unroll
    for (int t = 0; t < 12; ++t) z += lp[t] * rp[(size_t)t * NN_];
    sig2b[idx] = __float2bfloat16(1.f / (1.f + expf(-z)));
}

// ---------------- fp32 -> bf16 converters ----------------
__global__ __launch_bounds__(256) void k_cvt4(
    const float* __restrict__ src, unsigned short* __restrict__ dst)
{
    const int i = blockIdx.x * 256 + threadIdx.x;
    float4 v = ((const float4*)src)[i];
    ushort4 o;
    o.x = f2b(v.x); o.y = f2b(v.y); o.z = f2b(v.z); o.w = f2b(v.w);
    ((ushort4*)dst)[i] = o;
}

// ---------------- S = sig2 @ Vs^T, fused exp + colsum; store expS bf16 ----------------
__global__ __launch_bounds__(256) void k_gemm_s_mfma(
    const short* __restrict__ A,   // sig2b [B][1024][1024] bf16
    const short* __restrict__ Bm,  // Vsb   [1024][1024] bf16
    unsigned short* __restrict__ E, // expS bf16 out
    float* __restrict__ colsum)
{
    __shared__ short As[128 * 32];
    __shared__ short Bs[128 * 32];
    const int b  = blockIdx.z;
    const int i0 = blockIdx.y * 128;
    const int j0 = blockIdx.x * 128;
    const int tid = threadIdx.x;
    const int wid = tid >> 6;
    const int lane = tid & 63;
    const int wr = wid & 1, wc = wid >> 1;
    const short* Ab = A + (size_t)b * NN_ * NN_;

    f32x4 acc[4][4];
    const f32x4 z4 = {0.f, 0.f, 0.f, 0.f};
    #pragma unroll
    for (int m = 0; m < 4; ++m)
        #pragma unroll
        for (int n = 0; n < 4; ++n) acc[m][n] = z4;

    const int srow = lane >> 2;
    const int schk = lane & 3;
    const int fr = lane & 15;
    const int kb = (lane >> 4) * 8;

    for (int k0 = 0; k0 < NN_; k0 += 32) {
        #pragma unroll
        for (int q = 0; q < 2; ++q) {
            const int rb = (wid * 2 + q) * 16;
            const short* srcA = Ab + (size_t)(i0 + rb + srow) * NN_ + k0 + schk * 8;
            const short* srcB = Bm + (size_t)(j0 + rb + srow) * NN_ + k0 + schk * 8;
            __builtin_amdgcn_global_load_lds(
                (const __attribute__((address_space(1))) unsigned int*)srcA,
                (__attribute__((address_space(3))) unsigned int*)(As + rb * 32), 16, 0, 0);
            __builtin_amdgcn_global_load_lds(
                (const __attribute__((address_space(1))) unsigned int*)srcB,
                (__attribute__((address_space(3))) unsigned int*)(Bs + rb * 32), 16, 0, 0);
        }
        __syncthreads();
        bf16x8 aF[4], bF[4];
        #pragma unroll
        for (int m = 0; m < 4; ++m)
            aF[m] = *(const bf16x8*)(As + (wr*64 + m*16 + fr) * 32 + kb);
        #pragma unroll
        for (int n = 0; n < 4; ++n)
            bF[n] = *(const bf16x8*)(Bs + (wc*64 + n*16 + fr) * 32 + kb);
        #pragma unroll
        for (int m = 0; m < 4; ++m)
            #pragma unroll
            for (int n = 0; n < 4; ++n)
                acc[m][n] = __builtin_amdgcn_mfma_f32_16x16x32_bf16(aF[m], bF[n], acc[m][n], 0, 0, 0);
        __syncthreads();
    }
    unsigned short* Ep = E + (size_t)b * NN_ * NN_;
    const int cn = lane & 15;
    const int r0 = (lane >> 4) * 4;
    float cs[4] = {0.f, 0.f, 0.f, 0.f};
    #pragma unroll
    for (int m = 0; m < 4; ++m)
        #pragma unroll
        for (int n = 0; n < 4; ++n)
            #pragma unroll
            for (int r = 0; r < 4; ++r) {
                float e = __expf(acc[m][n][r]);
                Ep[(size_t)(i0 + wr*64 + m*16 + r0 + r) * NN_ + j0 + wc*64 + n*16 + cn] = f2b(e);
                cs[n] += e;
            }
    #pragma unroll
    for (int n = 0; n < 4; ++n) {
        float s = cs[n];
        s += __shfl_xor(s, 16);
        s += __shfl_xor(s, 32);
        if (lane < 16)
            atomicAdd(&colsum[b * NN_ + j0 + wc*64 + n*16 + cn], s);
    }
}

// ---- rhs_c partial[z][b,k,m,f,t] = sum_{n in half z} chebb[k,n,m]*expS[b,n,m]*rcs[m]*x[b,n,f,t] ----
__global__ __launch_bounds__(256) void k_rhsc(
    const unsigned short* __restrict__ chebb, const unsigned short* __restrict__ expS,
    const float* __restrict__ colsum, const float* __restrict__ x,
    float* __restrict__ rhsc)
{
    __shared__ float ch[3][16][64];
    __shared__ float st[16][64];
    __shared__ float xs[16][36];
    const int m0 = blockIdx.x * 64;
    const int b  = blockIdx.y;
    const int z  = blockIdx.z;
    const int nbase = z * 512;
    const int tid = threadIdx.x;
    const int m = tid >> 2, q = tid & 3;
    const int nn = tid >> 4, mm = (tid & 15) << 2;
    float4 rcs;
    {
        const float* cp = colsum + b * NN_ + m0 + mm;
        rcs.x = 1.f / cp[0]; rcs.y = 1.f / cp[1];
        rcs.z = 1.f / cp[2]; rcs.w = 1.f / cp[3];
    }
    float acc[3][9];
    #pragma unroll
    for (int k = 0; k < 3; ++k)
        #pragma unroll
        for (int jj = 0; jj < 9; ++jj) acc[k][jj] = 0.f;

    const unsigned short* sb = expS + (size_t)b * NN_ * NN_;
    const float* xb = x + (size_t)b * NN_ * 36;
    for (int n0 = nbase; n0 < nbase + 512; n0 += 16) {
        #pragma unroll
        for (int k = 0; k < 3; ++k) {
            ushort4 u = *(const ushort4*)(chebb + (size_t)k * NN_ * NN_ + (size_t)(n0 + nn) * NN_ + m0 + mm);
            ch[k][nn][mm+0] = b2f(u.x); ch[k][nn][mm+1] = b2f(u.y);
            ch[k][nn][mm+2] = b2f(u.z); ch[k][nn][mm+3] = b2f(u.w);
        }
        {
            ushort4 u = *(const ushort4*)(sb + (size_t)(n0 + nn) * NN_ + m0 + mm);
            st[nn][mm+0] = b2f(u.x) * rcs.x; st[nn][mm+1] = b2f(u.y) * rcs.y;
            st[nn][mm+2] = b2f(u.z) * rcs.z; st[nn][mm+3] = b2f(u.w) * rcs.w;
        }
        if (tid < 144) {
            int n2 = tid / 9, q2 = tid - n2 * 9;
            *(float4*)&xs[n2][q2*4] = *(const float4*)(xb + (size_t)(n0 + n2) * 36 + q2*4);
        }
        __syncthreads();
        #pragma unroll
        for (int u = 0; u < 16; ++u) {
            float xv[9];
            #pragma unroll
            for (int jj = 0; jj < 9; ++jj) xv[jj] = xs[u][q*9 + jj];
            const float sv = st[u][m];
            #pragma unroll
            for (int k = 0; k < 3; ++k) {
                const float w = ch[k][u][m] * sv;
                #pragma unroll
                for (int jj = 0; jj < 9; ++jj) acc[k][jj] += w * xv[jj];
            }
        }
        __syncthreads();
    }
    #pragma unroll
    for (int k = 0; k < 3; ++k) {
        float* rp = rhsc + (size_t)z * 1769472 + (((size_t)b*3 + k) * NN_ + m0 + m) * 36 + q*9;
        #pragma unroll
        for (int jj = 0; jj < 9; ++jj) rp[jj] = acc[k][jj];
    }
}

// ---- fused gcn + MFMA tconv + residual + relu + stats -> y ----
// 16 items/block. Gs rows = (i*12+t) [192], cols k=3*cp+d [192+pad]; Wt rows c [64].
#define GST 200
__global__ __launch_bounds__(256) void k_y4(
    const float* __restrict__ rhsc0, const float* __restrict__ rhsc1,
    const float* __restrict__ Theta, const float* __restrict__ x,
    const float* __restrict__ tcw, const float* __restrict__ tcb,
    const float* __restrict__ rcw, const float* __restrict__ rcb,
    float* __restrict__ y, float* __restrict__ acc)
{
    __shared__ unsigned short Gs[192 * GST];   // 76.8 KB
    __shared__ unsigned short Wt[64 * GST];    // 25.6 KB
    __shared__ float xls[16 * 36];             // 2.25 KB
    const int tid = threadIdx.x;
    const int wid = tid >> 6, lane = tid & 63;
    const int blk = blockIdx.x;                // items blk*16 .. +15

    // ---- stage Wt: contiguous dword runs (bank-conflict-free) ----
    {
        unsigned int* dst = (unsigned int*)Wt;
        #pragma unroll
        for (int idx = tid; idx < 6144; idx += 256) {
            const int row = idx / 96;          // 96 dwords (192 bf16) per row
            const int col2 = idx - row * 96;
            float2 v = *(const float2*)(tcw + idx * 2);
            dst[row * (GST/2) + col2] =
                (unsigned int)f2b(v.x) | ((unsigned int)f2b(v.y) << 16);
        }
    }
    if (tid < 144)
        ((float4*)xls)[tid] = ((const float4*)(x + (size_t)blk * 16 * 36))[tid];

    // ---- phase 1: gcn -> im2col Gs. wave wid: items 4*wid..+3, lane = cp ----
    {
        float th[9];
        #pragma unroll
        for (int j = 0; j < 9; ++j) th[j] = Theta[j * 64 + lane];
        #pragma unroll
        for (int ii = 0; ii < 4; ++ii) {
            const int i = wid * 4 + ii;
            const int bn = blk * 16 + i;
            const int b = bn >> 10, n = bn & 1023;
            float g[12];
            #pragma unroll
            for (int t = 0; t < 12; ++t) g[t] = 0.f;
            #pragma unroll
            for (int k = 0; k < 3; ++k) {
                const size_t off = (((size_t)b*3 + k) * NN_ + n) * 36;
                const float* p0 = rhsc0 + off;
                const float* p1 = rhsc1 + off;
                #pragma unroll
                for (int f = 0; f < 3; ++f) {
                    float4 a0 = *(const float4*)(p0 + f*12);
                    float4 a1 = *(const float4*)(p0 + f*12 + 4);
                    float4 a2 = *(const float4*)(p0 + f*12 + 8);
                    float4 b0 = *(const float4*)(p1 + f*12);
                    float4 b1 = *(const float4*)(p1 + f*12 + 4);
                    float4 b2 = *(const float4*)(p1 + f*12 + 8);
                    const float w = th[k*3 + f];
                    g[0] += (a0.x+b0.x)*w; g[1] += (a0.y+b0.y)*w;
                    g[2] += (a0.z+b0.z)*w; g[3] += (a0.w+b0.w)*w;
                    g[4] += (a1.x+b1.x)*w; g[5] += (a1.y+b1.y)*w;
                    g[6] += (a1.z+b1.z)*w; g[7] += (a1.w+b1.w)*w;
                    g[8] += (a2.x+b2.x)*w; g[9] += (a2.y+b2.y)*w;
                    g[10] += (a2.z+b2.z)*w; g[11] += (a2.w+b2.w)*w;
                }
            }
            unsigned short gb[14];
            gb[0] = 0; gb[13] = 0;
            #pragma unroll
            for (int t = 0; t < 12; ++t) gb[t+1] = f2b(fmaxf(g[t], 0.f));
            #pragma unroll
            for (int t = 0; t < 12; ++t) {
                unsigned short* p = Gs + (i*12 + t) * GST + 3*lane;
                p[0] = gb[t]; p[1] = gb[t+1]; p[2] = gb[t+2];
            }
        }
    }
    __syncthreads();

    // ---- phase 2: out[(i,t), c] = G @ W^T via MFMA; wave wid -> c-tile ----
    const int cl = lane & 15, kg = lane >> 4;
    const int c = wid * 16 + cl;
    bf16x8 bW[6];
    #pragma unroll
    for (int ks = 0; ks < 6; ++ks)
        bW[ks] = *(const bf16x8*)(Wt + c * GST + kg*8 + 32*ks);
    const float tb = tcb[c];
    const float rw0 = rcw[c*3], rw1 = rcw[c*3+1], rw2 = rcw[c*3+2];
    const float rbv = rcb[c];
    float ls = 0.f, lss = 0.f;
    #pragma unroll
    for (int rt = 0; rt < 12; ++rt) {
        f32x4 a4 = {0.f, 0.f, 0.f, 0.f};
        #pragma unroll
        for (int ks = 0; ks < 6; ++ks) {
            bf16x8 aF = *(const bf16x8*)(Gs + (rt*16 + cl) * GST + kg*8 + 32*ks);
            a4 = __builtin_amdgcn_mfma_f32_16x16x32_bf16(aF, bW[ks], a4, 0, 0, 0);
        }
        #pragma unroll
        for (int r = 0; r < 4; ++r) {
            const int nt = rt * 16 + kg * 4 + r;
            const int i = nt / 12;
            const int t = nt - i * 12;
            const float xres = rbv + xls[i*36 + t]*rw0 + xls[i*36 + 12 + t]*rw1 + xls[i*36 + 24 + t]*rw2;
            const float v = fmaxf(xres + a4[r] + tb, 0.f);
            ls += v; lss += v * v;
            y[(size_t)(blk*16 + i) * 768 + c * 12 + t] = v;
        }
    }
    ls  = wave_reduce_sum(ls);
    lss = wave_reduce_sum(lss);
    if (lane == 0) { atomicAdd(&acc[0], ls); atomicAdd(&acc[1], lss); }
}

// ---------------- finalize mean / inv_std ----------------
__global__ void k_fin(float* __restrict__ acc) {
    const float cnt = (float)((size_t)BB * NN_ * 64 * TT);
    float mu = acc[0] / cnt;
    float var = acc[1] / cnt - mu * mu;
    acc[2] = mu;
    acc[3] = rsqrtf(var + 1e-5f);
}

// ---------------- normalize in place on d_out ----------------
__global__ __launch_bounds__(256) void k_norm(
    float* __restrict__ y, const float* __restrict__ lng,
    const float* __restrict__ lnb, const float* __restrict__ acc)
{
    const unsigned int i = blockIdx.x * 256u + threadIdx.x;
    const float mu = acc[2], inv = acc[3];
    float4 v  = ((const float4*)y)[i];
    float4 gv = ((const float4*)lng)[i];
    float4 bv = ((const float4*)lnb)[i];
    v.x = (v.x - mu) * inv * gv.x + bv.x;
    v.y = (v.y - mu) * inv * gv.y + bv.y;
    v.z = (v.z - mu) * inv * gv.z + bv.z;
    v.w = (v.w - mu) * inv * gv.w + bv.w;
    ((float4*)y)[i] = v;
}

extern "C" void kernel_launch(void* const* d_in, const int* in_sizes, int n_in,
                              void* d_out, int out_size, void* d_ws, size_t ws_size,
                              hipStream_t stream)
{
    const float* x    = (const float*)d_in[0];
    const float* U1   = (const float*)d_in[1];
    const float* U2   = (const float*)d_in[2];
    const float* U3   = (const float*)d_in[3];
    const float* be   = (const float*)d_in[4];
    const float* Ve   = (const float*)d_in[5];
    const float* W1   = (const float*)d_in[6];
    const float* W2   = (const float*)d_in[7];
    const float* W3   = (const float*)d_in[8];
    const float* bs   = (const float*)d_in[9];
    const float* Vs   = (const float*)d_in[10];
    const float* cheb = (const float*)d_in[11];
    const float* Th   = (const float*)d_in[12];
    const float* tcw  = (const float*)d_in[13];
    const float* tcb  = (const float*)d_in[14];
    const float* rcw  = (const float*)d_in[15];
    const float* rcb  = (const float*)d_in[16];
    const float* lng  = (const float*)d_in[17];
    const float* lnb  = (const float*)d_in[18];
    float* out = (float*)d_out;
    float* ws  = (float*)d_ws;

    float* acc    = ws + ACC_OFF;
    float* colsum = ws + COLSUM_OFF;
    float* tat    = ws + TAT_OFF;
    float* lhsT   = ws + LHST_OFF;
    float* rhs2   = ws + RHS2_OFF;
    unsigned short* Vsb   = (unsigned short*)(ws + VSB_OFF);
    unsigned short* sig2b = (unsigned short*)(ws + SIG2B_OFF);
    unsigned short* chebb = (unsigned short*)(ws + CHEBB_OFF);
    unsigned short* expS  = (unsigned short*)(ws + EXPS_OFF);
    float* rhsc0  = ws + RHSC0_OFF;
    float* rhsc1  = ws + RHSC1_OFF;

    k_init<<<65, 256, 0, stream>>>(ws);
    k_temporal<<<BB, 64, 0, stream>>>(x, U1, U2, U3, be, Ve, tat);
    k_xtat<<<(BB * NN_) / 256, 256, 0, stream>>>(x, tat, W1, W2, W3, lhsT, rhs2);
    k_cvt4<<<(NN_ * NN_) / 1024, 256, 0, stream>>>(Vs, Vsb);
    k_cvt4<<<(3 * NN_ * NN_) / 1024, 256, 0, stream>>>(cheb, chebb);
    k_sig2<<<(BB * NN_ * NN_) / 256, 256, 0, stream>>>(lhsT, rhs2, bs, (__hip_bfloat16*)sig2b);
    k_gemm_s_mfma<<<dim3(8, 8, BB), 256, 0, stream>>>((const short*)sig2b, (const short*)Vsb, expS, colsum);
    k_rhsc<<<dim3(16, BB, 2), 256, 0, stream>>>(chebb, expS, colsum, x, rhsc0);
    k_y4<<<(BB * NN_) / 16, 256, 0, stream>>>(rhsc0, rhsc1, Th, x, tcw, tcb, rcw, rcb, out, acc);
    k_fin<<<1, 1, 0, stream>>>(acc);
    k_norm<<<(BB * NN_ * 64 * TT) / 4 / 256, 256, 0, stream>>>(out, lng, lnb, acc);
}

// Round 5
// 540.820 us; speedup vs baseline: 1.3704x; 1.0021x over previous
//
#include <hip/hip_runtime.h>
#include <hip/hip_bf16.h>
#include <math.h>

#define BB 16
#define NN_ 1024
#define TT 12

typedef __attribute__((ext_vector_type(8))) short bf16x8;
typedef __attribute__((ext_vector_type(4))) float f32x4;

// ---------------- workspace layout (float units) ----------------
static const size_t ACC_OFF    = 0;          // 16
static const size_t COLSUM_OFF = 16;         // B*N = 16384
static const size_t TAT_OFF    = 16400;      // B*T*T = 2304
static const size_t LHST_OFF   = 18704;      // B*N*T = 196608
static const size_t RHS2_OFF   = 215312;     // B*T*N = 196608
static const size_t VSB_OFF    = 411920;     // N*N bf16 = 524288 floats
static const size_t SIG2B_OFF  = 936208;     // B*N*N bf16 = 8388608 floats
static const size_t CHEBB_OFF  = 9324816;    // 3*N*N bf16 = 1572864 floats
static const size_t EXPS_OFF   = 10897680;   // B*N*N bf16 = 8388608 floats
static const size_t RHSC0_OFF  = 19286288;   // B*K*N*F*T fp32 = 1769472
static const size_t RHSC1_OFF  = 21055760;   // B*K*N*F*T fp32 = 1769472
// total 22825232 floats = ~91 MB

__device__ __forceinline__ float wave_reduce_sum(float v) {
    #pragma unroll
    for (int off = 32; off > 0; off >>= 1) v += __shfl_down(v, off);
    return v;
}

__device__ __forceinline__ unsigned short f2b(float f) {
    __hip_bfloat16 h = __float2bfloat16(f);
    return *(unsigned short*)&h;
}
__device__ __forceinline__ float b2f(unsigned short u) {
    return __uint_as_float(((unsigned int)u) << 16);
}

// ---------------- init: zero acc + colsum ----------------
__global__ void k_init(float* __restrict__ ws) {
    int i = blockIdx.x * 256 + threadIdx.x;
    if (i < 16400) ws[i] = 0.f;
}

// ---------------- temporal attention -> tat (B,T,T), 256 threads ----------------
__global__ __launch_bounds__(256) void k_temporal(
    const float* __restrict__ x, const float* __restrict__ U1,
    const float* __restrict__ U2, const float* __restrict__ U3,
    const float* __restrict__ be, const float* __restrict__ Ve,
    float* __restrict__ tat)
{
    const int b = blockIdx.x;
    const int tid = threadIdx.x;
    const int wid = tid >> 6, lane = tid & 63;
    float lA[36], lM[36];
    #pragma unroll
    for (int i = 0; i < 36; ++i) { lA[i] = 0.f; lM[i] = 0.f; }
    const float u30 = U3[0], u31 = U3[1], u32 = U3[2];
    for (int n = tid; n < NN_; n += 256) {
        const float* xp = x + ((size_t)b * NN_ + n) * 36;
        float xr[36];
        #pragma unroll
        for (int i = 0; i < 9; ++i) *(float4*)&xr[i*4] = *(const float4*)(xp + i*4);
        const float u1  = U1[n];
        const float u20 = U2[n], u21 = U2[NN_ + n], u22 = U2[2*NN_ + n];
        #pragma unroll
        for (int t = 0; t < 12; ++t) {
            float ru = xr[t]*u30 + xr[12+t]*u31 + xr[24+t]*u32;
            lM[t]    += u20 * ru;
            lM[12+t] += u21 * ru;
            lM[24+t] += u22 * ru;
            lA[t]    += xr[t]    * u1;
            lA[12+t] += xr[12+t] * u1;
            lA[24+t] += xr[24+t] * u1;
        }
    }
    __shared__ float pA[4][36], pM[4][36];
    __shared__ float tA[36], tM[36], sgs[144], es[144], cmax[12], csum[12];
    #pragma unroll
    for (int i = 0; i < 36; ++i) {
        float v = wave_reduce_sum(lA[i]);
        if (lane == 0) pA[wid][i] = v;
        float w = wave_reduce_sum(lM[i]);
        if (lane == 0) pM[wid][i] = w;
    }
    __syncthreads();
    if (tid < 36) tA[tid] = pA[0][tid] + pA[1][tid] + pA[2][tid] + pA[3][tid];
    else if (tid < 72) {
        int i = tid - 36;
        tM[i] = pM[0][i] + pM[1][i] + pM[2][i] + pM[3][i];
    }
    __syncthreads();
    if (tid < 144) {
        int idx = tid;
        int t = idx / 12, u = idx % 12;
        float p = tA[t]*tM[u] + tA[12+t]*tM[12+u] + tA[24+t]*tM[24+u];
        p += be[idx];
        sgs[idx] = 1.f / (1.f + expf(-p));
    }
    __syncthreads();
    if (tid < 144) {
        int i = tid / 12, j = tid % 12;
        float e = 0.f;
        #pragma unroll
        for (int k = 0; k < 12; ++k) e += sgs[i*12 + k] * Ve[j*12 + k];
        es[tid] = e;
    }
    __syncthreads();
    if (tid < 12) {
        int j = tid;
        float m = -1e30f;
        for (int i = 0; i < 12; ++i) m = fmaxf(m, es[i*12 + j]);
        float sx = 0.f;
        for (int i = 0; i < 12; ++i) sx += expf(es[i*12 + j] - m);
        cmax[j] = m; csum[j] = sx;
    }
    __syncthreads();
    if (tid < 144) {
        int j = tid % 12;
        tat[(size_t)b*144 + tid] = expf(es[tid] - cmax[j]) / csum[j];
    }
}

// ---------------- x_tat projections -> lhsT (B,N,T), rhs2 (B,T,N) ----------------
__global__ __launch_bounds__(256) void k_xtat(
    const float* __restrict__ x, const float* __restrict__ tat,
    const float* __restrict__ W1, const float* __restrict__ W2,
    const float* __restrict__ W3,
    float* __restrict__ lhsT, float* __restrict__ rhs2)
{
    const int id = blockIdx.x * 256 + threadIdx.x;
    const int b = id >> 10, n = id & 1023;
    const float* xp = x + (size_t)id * 36;
    float xr[36];
    #pragma unroll
    for (int i = 0; i < 9; ++i) *(float4*)&xr[i*4] = *(const float4*)(xp + i*4);
    const float* tp = tat + (size_t)b * 144;
    float xt[36];
    #pragma unroll
    for (int f = 0; f < 3; ++f)
        #pragma unroll
        for (int u = 0; u < 12; ++u) {
            float s = 0.f;
            #pragma unroll
            for (int t = 0; t < 12; ++t) s += xr[f*12 + t] * tp[t*12 + u];
            xt[f*12 + u] = s;
        }
    float lA0 = 0.f, lA1 = 0.f, lA2 = 0.f;
    #pragma unroll
    for (int t = 0; t < 12; ++t) {
        float w = W1[t];
        lA0 += xt[t]*w; lA1 += xt[12+t]*w; lA2 += xt[24+t]*w;
    }
    #pragma unroll
    for (int t2 = 0; t2 < 12; ++t2)
        lhsT[(size_t)id*12 + t2] = lA0*W2[t2] + lA1*W2[12+t2] + lA2*W2[24+t2];
    const float w30 = W3[0], w31 = W3[1], w32 = W3[2];
    #pragma unroll
    for (int u = 0; u < 12; ++u)
        rhs2[((size_t)b*12 + u)*NN_ + n] = xt[u]*w30 + xt[12+u]*w31 + xt[24+u]*w32;
}

// ---------------- sig2 (B,N,N) -> bf16 ----------------
__global__ __launch_bounds__(256) void k_sig2(
    const float* __restrict__ lhsT, const float* __restrict__ rhs2,
    const float* __restrict__ bs, __hip_bfloat16* __restrict__ sig2b)
{
    const unsigned int idx = blockIdx.x * 256u + threadIdx.x;
    const int m = (int)(idx & 1023u);
    const unsigned int bn = idx >> 10;
    const int b = (int)(bn >> 10);
    const int n = (int)(bn & 1023u);
    const float* lp = lhsT + (size_t)bn * 12;
    const float* rp = rhs2 + (size_t)b * 12 * NN_ + m;
    float z = bs[(size_t)n * NN_ + m];
    #pragma unroll
    for (int t = 0; t < 12; ++t) z += lp[t] * rp[(size_t)t * NN_];
    sig2b[idx] = __float2bfloat16(1.f / (1.f + expf(-z)));
}

// ---------------- fp32 -> bf16 converters ----------------
__global__ __launch_bounds__(256) void k_cvt4(
    const float* __restrict__ src, unsigned short* __restrict__ dst)
{
    const int i = blockIdx.x * 256 + threadIdx.x;
    float4 v = ((const float4*)src)[i];
    ushort4 o;
    o.x = f2b(v.x); o.y = f2b(v.y); o.z = f2b(v.z); o.w = f2b(v.w);
    ((ushort4*)dst)[i] = o;
}

// ---------------- S = sig2 @ Vs^T, fused exp + colsum; store expS bf16 ----------------
__global__ __launch_bounds__(256) void k_gemm_s_mfma(
    const short* __restrict__ A,   // sig2b [B][1024][1024] bf16
    const short* __restrict__ Bm,  // Vsb   [1024][1024] bf16
    unsigned short* __restrict__ E, // expS bf16 out
    float* __restrict__ colsum)
{
    __shared__ short As[128 * 32];
    __shared__ short Bs[128 * 32];
    const int b  = blockIdx.z;
    const int i0 = blockIdx.y * 128;
    const int j0 = blockIdx.x * 128;
    const int tid = threadIdx.x;
    const int wid = tid >> 6;
    const int lane = tid & 63;
    const int wr = wid & 1, wc = wid >> 1;
    const short* Ab = A + (size_t)b * NN_ * NN_;

    f32x4 acc[4][4];
    const f32x4 z4 = {0.f, 0.f, 0.f, 0.f};
    #pragma unroll
    for (int m = 0; m < 4; ++m)
        #pragma unroll
        for (int n = 0; n < 4; ++n) acc[m][n] = z4;

    const int srow = lane >> 2;
    const int schk = lane & 3;
    const int fr = lane & 15;
    const int kb = (lane >> 4) * 8;

    for (int k0 = 0; k0 < NN_; k0 += 32) {
        #pragma unroll
        for (int q = 0; q < 2; ++q) {
            const int rb = (wid * 2 + q) * 16;
            const short* srcA = Ab + (size_t)(i0 + rb + srow) * NN_ + k0 + schk * 8;
            const short* srcB = Bm + (size_t)(j0 + rb + srow) * NN_ + k0 + schk * 8;
            __builtin_amdgcn_global_load_lds(
                (const __attribute__((address_space(1))) unsigned int*)srcA,
                (__attribute__((address_space(3))) unsigned int*)(As + rb * 32), 16, 0, 0);
            __builtin_amdgcn_global_load_lds(
                (const __attribute__((address_space(1))) unsigned int*)srcB,
                (__attribute__((address_space(3))) unsigned int*)(Bs + rb * 32), 16, 0, 0);
        }
        __syncthreads();
        bf16x8 aF[4], bF[4];
        #pragma unroll
        for (int m = 0; m < 4; ++m)
            aF[m] = *(const bf16x8*)(As + (wr*64 + m*16 + fr) * 32 + kb);
        #pragma unroll
        for (int n = 0; n < 4; ++n)
            bF[n] = *(const bf16x8*)(Bs + (wc*64 + n*16 + fr) * 32 + kb);
        #pragma unroll
        for (int m = 0; m < 4; ++m)
            #pragma unroll
            for (int n = 0; n < 4; ++n)
                acc[m][n] = __builtin_amdgcn_mfma_f32_16x16x32_bf16(aF[m], bF[n], acc[m][n], 0, 0, 0);
        __syncthreads();
    }
    unsigned short* Ep = E + (size_t)b * NN_ * NN_;
    const int cn = lane & 15;
    const int r0 = (lane >> 4) * 4;
    float cs[4] = {0.f, 0.f, 0.f, 0.f};
    #pragma unroll
    for (int m = 0; m < 4; ++m)
        #pragma unroll
        for (int n = 0; n < 4; ++n)
            #pragma unroll
            for (int r = 0; r < 4; ++r) {
                float e = __expf(acc[m][n][r]);
                Ep[(size_t)(i0 + wr*64 + m*16 + r0 + r) * NN_ + j0 + wc*64 + n*16 + cn] = f2b(e);
                cs[n] += e;
            }
    #pragma unroll
    for (int n = 0; n < 4; ++n) {
        float s = cs[n];
        s += __shfl_xor(s, 16);
        s += __shfl_xor(s, 32);
        if (lane < 16)
            atomicAdd(&colsum[b * NN_ + j0 + wc*64 + n*16 + cn], s);
    }
}

// ---- rhs_c partial[z][b,k,m,f,t] = sum_{n in half z} chebb[k,n,m]*expS[b,n,m]*rcs[m]*x[b,n,f,t] ----
__global__ __launch_bounds__(256) void k_rhsc(
    const unsigned short* __restrict__ chebb, const unsigned short* __restrict__ expS,
    const float* __restrict__ colsum, const float* __restrict__ x,
    float* __restrict__ rhsc)
{
    __shared__ float ch[3][16][64];
    __shared__ float st[16][64];
    __shared__ float xs[16][36];
    const int m0 = blockIdx.x * 64;
    const int b  = blockIdx.y;
    const int z  = blockIdx.z;
    const int nbase = z * 512;
    const int tid = threadIdx.x;
    const int m = tid >> 2, q = tid & 3;
    const int nn = tid >> 4, mm = (tid & 15) << 2;
    float4 rcs;
    {
        const float* cp = colsum + b * NN_ + m0 + mm;
        rcs.x = 1.f / cp[0]; rcs.y = 1.f / cp[1];
        rcs.z = 1.f / cp[2]; rcs.w = 1.f / cp[3];
    }
    float acc[3][9];
    #pragma unroll
    for (int k = 0; k < 3; ++k)
        #pragma unroll
        for (int jj = 0; jj < 9; ++jj) acc[k][jj] = 0.f;

    const unsigned short* sb = expS + (size_t)b * NN_ * NN_;
    const float* xb = x + (size_t)b * NN_ * 36;
    for (int n0 = nbase; n0 < nbase + 512; n0 += 16) {
        #pragma unroll
        for (int k = 0; k < 3; ++k) {
            ushort4 u = *(const ushort4*)(chebb + (size_t)k * NN_ * NN_ + (size_t)(n0 + nn) * NN_ + m0 + mm);
            ch[k][nn][mm+0] = b2f(u.x); ch[k][nn][mm+1] = b2f(u.y);
            ch[k][nn][mm+2] = b2f(u.z); ch[k][nn][mm+3] = b2f(u.w);
        }
        {
            ushort4 u = *(const ushort4*)(sb + (size_t)(n0 + nn) * NN_ + m0 + mm);
            st[nn][mm+0] = b2f(u.x) * rcs.x; st[nn][mm+1] = b2f(u.y) * rcs.y;
            st[nn][mm+2] = b2f(u.z) * rcs.z; st[nn][mm+3] = b2f(u.w) * rcs.w;
        }
        if (tid < 144) {
            int n2 = tid / 9, q2 = tid - n2 * 9;
            *(float4*)&xs[n2][q2*4] = *(const float4*)(xb + (size_t)(n0 + n2) * 36 + q2*4);
        }
        __syncthreads();
        #pragma unroll
        for (int u = 0; u < 16; ++u) {
            float xv[9];
            #pragma unroll
            for (int jj = 0; jj < 9; ++jj) xv[jj] = xs[u][q*9 + jj];
            const float sv = st[u][m];
            #pragma unroll
            for (int k = 0; k < 3; ++k) {
                const float w = ch[k][u][m] * sv;
                #pragma unroll
                for (int jj = 0; jj < 9; ++jj) acc[k][jj] += w * xv[jj];
            }
        }
        __syncthreads();
    }
    #pragma unroll
    for (int k = 0; k < 3; ++k) {
        float* rp = rhsc + (size_t)z * 1769472 + (((size_t)b*3 + k) * NN_ + m0 + m) * 36 + q*9;
        #pragma unroll
        for (int jj = 0; jj < 9; ++jj) rp[jj] = acc[k][jj];
    }
}

// ---- fused gcn + tconv-as-3-shifted-GEMMs + residual + relu + stats -> y ----
// out[nt,c] = sum_d sum_cp Gs2[nt+d-1][cp] * Wd[d][c][cp]  (zero row for t-boundaries)
#define G2S 72            // Gs2 row stride (halfwords): 64 + 8 pad
__global__ __launch_bounds__(256) void k_y5(
    const float* __restrict__ rhsc0, const float* __restrict__ rhsc1,
    const float* __restrict__ Theta, const float* __restrict__ x,
    const float* __restrict__ tcw, const float* __restrict__ tcb,
    const float* __restrict__ rcw, const float* __restrict__ rcb,
    float* __restrict__ y, float* __restrict__ acc)
{
    __shared__ unsigned short Gs2[193 * G2S];   // rows 0..191 = nt, row 192 = zeros; 27.8 KB
    __shared__ unsigned short Wt2[192 * G2S];   // rows d*64+c; 27.6 KB
    __shared__ float xls[16 * 36];              // 2.25 KB
    const int tid = threadIdx.x;
    const int wid = tid >> 6, lane = tid & 63;
    const int blk = blockIdx.x;                 // items blk*16 .. +15

    // ---- stage Wt2[d][c][cp] = tcw[c][3cp+d] (bf16), once per block ----
    for (int idx = tid; idx < 12288; idx += 256) {
        const int c = idx / 192;
        const int k = idx - c * 192;
        const int cp = k / 3;
        const int d = k - 3 * cp;
        Wt2[(d * 64 + c) * G2S + cp] = f2b(tcw[idx]);
    }
    // zero row
    if (tid < 36) ((unsigned int*)(Gs2 + 192 * G2S))[tid] = 0u;
    if (tid < 144)
        ((float4*)xls)[tid] = ((const float4*)(x + (size_t)blk * 16 * 36))[tid];

    // ---- phase 1: gcn -> Gs2[nt][cp]. wave wid: items 4*wid..+3, lane = cp ----
    {
        float th[9];
        #pragma unroll
        for (int j = 0; j < 9; ++j) th[j] = Theta[j * 64 + lane];
        #pragma unroll
        for (int ii = 0; ii < 4; ++ii) {
            const int i = wid * 4 + ii;
            const int bn = blk * 16 + i;
            const int b = bn >> 10, n = bn & 1023;
            float g[12];
            #pragma unroll
            for (int t = 0; t < 12; ++t) g[t] = 0.f;
            #pragma unroll
            for (int k = 0; k < 3; ++k) {
                const size_t off = (((size_t)b*3 + k) * NN_ + n) * 36;
                const float* p0 = rhsc0 + off;
                const float* p1 = rhsc1 + off;
                #pragma unroll
                for (int f = 0; f < 3; ++f) {
                    float4 a0 = *(const float4*)(p0 + f*12);
                    float4 a1 = *(const float4*)(p0 + f*12 + 4);
                    float4 a2 = *(const float4*)(p0 + f*12 + 8);
                    float4 b0 = *(const float4*)(p1 + f*12);
                    float4 b1 = *(const float4*)(p1 + f*12 + 4);
                    float4 b2 = *(const float4*)(p1 + f*12 + 8);
                    const float w = th[k*3 + f];
                    g[0] += (a0.x+b0.x)*w; g[1] += (a0.y+b0.y)*w;
                    g[2] += (a0.z+b0.z)*w; g[3] += (a0.w+b0.w)*w;
                    g[4] += (a1.x+b1.x)*w; g[5] += (a1.y+b1.y)*w;
                    g[6] += (a1.z+b1.z)*w; g[7] += (a1.w+b1.w)*w;
                    g[8] += (a2.x+b2.x)*w; g[9] += (a2.y+b2.y)*w;
                    g[10] += (a2.z+b2.z)*w; g[11] += (a2.w+b2.w)*w;
                }
            }
            #pragma unroll
            for (int t = 0; t < 12; ++t)
                Gs2[(i*12 + t) * G2S + lane] = f2b(fmaxf(g[t], 0.f));
        }
    }
    __syncthreads();

    // ---- phase 2: 3 shifted GEMMs. wave wid -> c-tile; 72 MFMA/wave ----
    const int cl = lane & 15, kg = lane >> 4;
    const int c = wid * 16 + cl;
    bf16x8 bW[3][2];
    #pragma unroll
    for (int d = 0; d < 3; ++d)
        #pragma unroll
        for (int kb = 0; kb < 2; ++kb)
            bW[d][kb] = *(const bf16x8*)(Wt2 + (d*64 + c) * G2S + kb*32 + kg*8);
    const float tb = tcb[c];
    const float rw0 = rcw[c*3], rw1 = rcw[c*3+1], rw2 = rcw[c*3+2];
    const float rbv = rcb[c];
    float ls = 0.f, lss = 0.f;
    #pragma unroll
    for (int rt = 0; rt < 12; ++rt) {
        const int nt = rt * 16 + cl;
        const int t = nt - (nt / 12) * 12;
        const unsigned short* g1 = Gs2 + nt * G2S + kg * 8;
        const unsigned short* g0 = (t == 0)  ? (Gs2 + 192 * G2S + kg * 8) : (g1 - G2S);
        const unsigned short* g2 = (t == 11) ? (Gs2 + 192 * G2S + kg * 8) : (g1 + G2S);
        f32x4 a4 = {0.f, 0.f, 0.f, 0.f};
        #pragma unroll
        for (int kb = 0; kb < 2; ++kb) {
            a4 = __builtin_amdgcn_mfma_f32_16x16x32_bf16(*(const bf16x8*)(g0 + kb*32), bW[0][kb], a4, 0, 0, 0);
            a4 = __builtin_amdgcn_mfma_f32_16x16x32_bf16(*(const bf16x8*)(g1 + kb*32), bW[1][kb], a4, 0, 0, 0);
            a4 = __builtin_amdgcn_mfma_f32_16x16x32_bf16(*(const bf16x8*)(g2 + kb*32), bW[2][kb], a4, 0, 0, 0);
        }
        #pragma unroll
        for (int r = 0; r < 4; ++r) {
            const int nto = rt * 16 + kg * 4 + r;
            const int i = nto / 12;
            const int tt = nto - i * 12;
            const float xres = rbv + xls[i*36 + tt]*rw0 + xls[i*36 + 12 + tt]*rw1 + xls[i*36 + 24 + tt]*rw2;
            const float v = fmaxf(xres + a4[r] + tb, 0.f);
            ls += v; lss += v * v;
            y[(size_t)(blk*16 + i) * 768 + c * 12 + tt] = v;
        }
    }
    ls  = wave_reduce_sum(ls);
    lss = wave_reduce_sum(lss);
    if (lane == 0) { atomicAdd(&acc[0], ls); atomicAdd(&acc[1], lss); }
}

// ---------------- finalize mean / inv_std ----------------
__global__ void k_fin(float* __restrict__ acc) {
    const float cnt = (float)((size_t)BB * NN_ * 64 * TT);
    float mu = acc[0] / cnt;
    float var = acc[1] / cnt - mu * mu;
    acc[2] = mu;
    acc[3] = rsqrtf(var + 1e-5f);
}

// ---------------- normalize in place on d_out ----------------
__global__ __launch_bounds__(256) void k_norm(
    float* __restrict__ y, const float* __restrict__ lng,
    const float* __restrict__ lnb, const float* __restrict__ acc)
{
    const unsigned int i = blockIdx.x * 256u + threadIdx.x;
    const float mu = acc[2], inv = acc[3];
    float4 v  = ((const float4*)y)[i];
    float4 gv = ((const float4*)lng)[i];
    float4 bv = ((const float4*)lnb)[i];
    v.x = (v.x - mu) * inv * gv.x + bv.x;
    v.y = (v.y - mu) * inv * gv.y + bv.y;
    v.z = (v.z - mu) * inv * gv.z + bv.z;
    v.w = (v.w - mu) * inv * gv.w + bv.w;
    ((float4*)y)[i] = v;
}

extern "C" void kernel_launch(void* const* d_in, const int* in_sizes, int n_in,
                              void* d_out, int out_size, void* d_ws, size_t ws_size,
                              hipStream_t stream)
{
    const float* x    = (const float*)d_in[0];
    const float* U1   = (const float*)d_in[1];
    const float* U2   = (const float*)d_in[2];
    const float* U3   = (const float*)d_in[3];
    const float* be   = (const float*)d_in[4];
    const float* Ve   = (const float*)d_in[5];
    const float* W1   = (const float*)d_in[6];
    const float* W2   = (const float*)d_in[7];
    const float* W3   = (const float*)d_in[8];
    const float* bs   = (const float*)d_in[9];
    const float* Vs   = (const float*)d_in[10];
    const float* cheb = (const float*)d_in[11];
    const float* Th   = (const float*)d_in[12];
    const float* tcw  = (const float*)d_in[13];
    const float* tcb  = (const float*)d_in[14];
    const float* rcw  = (const float*)d_in[15];
    const float* rcb  = (const float*)d_in[16];
    const float* lng  = (const float*)d_in[17];
    const float* lnb  = (const float*)d_in[18];
    float* out = (float*)d_out;
    float* ws  = (float*)d_ws;

    float* acc    = ws + ACC_OFF;
    float* colsum = ws + COLSUM_OFF;
    float* tat    = ws + TAT_OFF;
    float* lhsT   = ws + LHST_OFF;
    float* rhs2   = ws + RHS2_OFF;
    unsigned short* Vsb   = (unsigned short*)(ws + VSB_OFF);
    unsigned short* sig2b = (unsigned short*)(ws + SIG2B_OFF);
    unsigned short* chebb = (unsigned short*)(ws + CHEBB_OFF);
    unsigned short* expS  = (unsigned short*)(ws + EXPS_OFF);
    float* rhsc0  = ws + RHSC0_OFF;
    float* rhsc1  = ws + RHSC1_OFF;

    k_init<<<65, 256, 0, stream>>>(ws);
    k_temporal<<<BB, 256, 0, stream>>>(x, U1, U2, U3, be, Ve, tat);
    k_xtat<<<(BB * NN_) / 256, 256, 0, stream>>>(x, tat, W1, W2, W3, lhsT, rhs2);
    k_cvt4<<<(NN_ * NN_) / 1024, 256, 0, stream>>>(Vs, Vsb);
    k_cvt4<<<(3 * NN_ * NN_) / 1024, 256, 0, stream>>>(cheb, chebb);
    k_sig2<<<(BB * NN_ * NN_) / 256, 256, 0, stream>>>(lhsT, rhs2, bs, (__hip_bfloat16*)sig2b);
    k_gemm_s_mfma<<<dim3(8, 8, BB), 256, 0, stream>>>((const short*)sig2b, (const short*)Vsb, expS, colsum);
    k_rhsc<<<dim3(16, BB, 2), 256, 0, stream>>>(chebb, expS, colsum, x, rhsc0);
    k_y5<<<(BB * NN_) / 16, 256, 0, stream>>>(rhsc0, rhsc1, Th, x, tcw, tcb, rcw, rcb, out, acc);
    k_fin<<<1, 1, 0, stream>>>(acc);
    k_norm<<<(BB * NN_ * 64 * TT) / 4 / 256, 256, 0, stream>>>(out, lng, lnb, acc);
}